// Round 14
// baseline (263.743 us; speedup 1.0000x reference)
//
#include <hip/hip_runtime.h>
#include <math.h>

#define N_NODES 50000
#define N_EDGES 800000
#define IN_C 16
#define HID_C 16
#define OUT_C 10
#define N_GRAPHS 500
#define EDGE_DIM 3
#define MLP_HID 25
#define BN_EPS 1e-5f

#define SCAN_NB ((N_NODES + 255) / 256)   // 196 blocks

typedef __attribute__((ext_vector_type(8))) _Float16 half8;
typedef __attribute__((ext_vector_type(2))) _Float16 half2v;
typedef __attribute__((ext_vector_type(4))) float f32x4;
union U4H8 { uint4 u; half8 h; half2v p[4]; };
union HU { _Float16 h; unsigned short u; };
union H2U2 { half2v p[2]; uint2 u; };

// ---------------- setup: W-pack(f16) + BN-fold + goff + zero CNT/flags -------

// blk 0..6  : pack W' = [Wb rows (k'=k*16+i, k<25) ; bb rows (k'=400+i)]
//             (416x16) into per-MFMA per-lane f16 fragments (RNE).
//             Element j of (m, lane L): row k'=32m+8(L>>4)+j, col o=L&15.
//             (Same data serves as the A-operand W'^T fragment — verified R13.)
// blk 7     : fold BN into AC[k][4]={A0,A1,A2,C} (k<25), AC[25]={0,0,0,1};
// blk 7..8  : goff[g] = lower_bound(batch, g) (batch sorted)
// blk 9..204: zero CNT; blk 9 also zeroes the scan lookback flags
__global__ __launch_bounds__(256) void setup_kernel(
    const float* __restrict__ W1a, const float* __restrict__ b1a,
    const float* __restrict__ g1, const float* __restrict__ bt1,
    const float* __restrict__ m1, const float* __restrict__ v1,
    const float* __restrict__ W2a, const float* __restrict__ b2a,
    const float* __restrict__ g2, const float* __restrict__ bt2,
    const float* __restrict__ m2, const float* __restrict__ v2,
    const float* __restrict__ W1b, const float* __restrict__ b1b,
    const float* __restrict__ W2b, const float* __restrict__ b2b,
    const int* __restrict__ batch,
    float* __restrict__ AC1, float* __restrict__ AC2,
    unsigned int* __restrict__ WF1, unsigned int* __restrict__ WF2,
    int* __restrict__ goff, int* __restrict__ cnt, int* __restrict__ flag)
{
    const int blk = blockIdx.x;
    const int tid = threadIdx.x;
    if (blk < 7) {
        int t = blk * 256 + tid;
        if (t >= 1664) return;
        const float *Wb, *bb; unsigned int *WH;
        int tl = t;
        if (t < 832) { Wb = W1b; bb = b1b; WH = WF1; }
        else { tl = t - 832; Wb = W2b; bb = b2b; WH = WF2; }
        int m = tl >> 6;
        int L = tl & 63;
        int q = L >> 4, o = L & 15;
        unsigned int hi[8];
        for (int j = 0; j < 8; ++j) {
            int kp = m*32 + q*8 + j;          // 0..415
            int k = kp >> 4, i = kp & 15;
            float w = (k < 25) ? Wb[k*256 + i*16 + o] : bb[i*16 + o];
            HU cv; cv.h = (_Float16)w;        // f16 RNE
            hi[j] = cv.u;
        }
        int base = (m*64 + L) * 4;
        for (int d = 0; d < 4; ++d)
            WH[base + d] = hi[2*d] | (hi[2*d+1] << 16);
        return;
    }
    if (blk == 7 || blk == 8) {
        if (blk == 7) {
            if (tid < 26) {
                int k = tid;
                if (k < 25) {
                    float sc = g1[k] / sqrtf(v1[k] + BN_EPS);
                    AC1[k*4+0] = sc * W1a[0*MLP_HID+k];
                    AC1[k*4+1] = sc * W1a[1*MLP_HID+k];
                    AC1[k*4+2] = sc * W1a[2*MLP_HID+k];
                    AC1[k*4+3] = sc * (b1a[k] - m1[k]) + bt1[k];
                } else {
                    AC1[100] = 0.f; AC1[101] = 0.f; AC1[102] = 0.f; AC1[103] = 1.f;
                }
            } else if (tid >= 32 && tid < 58) {
                int k = tid - 32;
                if (k < 25) {
                    float sc = g2[k] / sqrtf(v2[k] + BN_EPS);
                    AC2[k*4+0] = sc * W2a[0*MLP_HID+k];
                    AC2[k*4+1] = sc * W2a[1*MLP_HID+k];
                    AC2[k*4+2] = sc * W2a[2*MLP_HID+k];
                    AC2[k*4+3] = sc * (b2a[k] - m2[k]) + bt2[k];
                } else {
                    AC2[100] = 0.f; AC2[101] = 0.f; AC2[102] = 0.f; AC2[103] = 1.f;
                }
            }
        }
        int g = (blk - 7) * 256 + tid;
        if (g <= N_GRAPHS) {
            int lo = 0, hi = N_NODES;
            while (lo < hi) {
                int mid = (lo + hi) >> 1;
                if (batch[mid] < g) lo = mid + 1; else hi = mid;
            }
            goff[g] = lo;
        }
        return;
    }
    int idx = (blk - 9) * 256 + tid;
    if (idx < N_NODES) cnt[idx] = 0;
    if (blk == 9 && tid < SCAN_NB) flag[tid] = 0;
}

// ---------------- CSR build ----------------

__global__ __launch_bounds__(256) void rank_kernel(const int* __restrict__ dst,
                                                   int* __restrict__ cnt,
                                                   int* __restrict__ rank) {
    int e = blockIdx.x * blockDim.x + threadIdx.x;
    if (e < N_EDGES) rank[e] = atomicAdd(&cnt[dst[e]], 1);
}

// single-pass exclusive scan of cnt -> off[0..N] via decoupled lookback.
// flag[b]: 0=none, 1=aggregate ready (agg[b]), 2=inclusive prefix ready (pre[b]).
// All 196 blocks are co-resident on 256 CUs -> lookback cannot deadlock.
__global__ __launch_bounds__(256) void scan_single(const int* __restrict__ cnt,
                                                   int* __restrict__ off,
                                                   int* __restrict__ agg,
                                                   int* __restrict__ pre,
                                                   int* __restrict__ flag) {
    __shared__ int lds[256];
    __shared__ int sExc;
    const int b = blockIdx.x, t = threadIdx.x;
    const int idx = b * 256 + t;
    const int v = (idx < N_NODES) ? cnt[idx] : 0;
    lds[t] = v;
    __syncthreads();
    for (int d = 1; d < 256; d <<= 1) {
        int u = (t >= d) ? lds[t - d] : 0;
        __syncthreads();
        lds[t] += u;
        __syncthreads();
    }
    const int total = lds[255];
    if (t == 0) {
        int exc = 0;
        if (b == 0) {
            atomicExch(&pre[0], total);
            __threadfence();
            atomicExch(&flag[0], 2);
        } else {
            atomicExch(&agg[b], total);
            __threadfence();
            atomicExch(&flag[b], 1);
            int j = b - 1;
            while (true) {
                int f;
                do { f = atomicAdd(&flag[j], 0); } while (f == 0);
                if (f == 2) { exc += atomicAdd(&pre[j], 0); break; }
                exc += atomicAdd(&agg[j], 0);
                --j;
            }
            atomicExch(&pre[b], exc + total);
            __threadfence();
            atomicExch(&flag[b], 2);
        }
        sExc = exc;
    }
    __syncthreads();
    const int exc = sExc;
    if (idx < N_NODES) off[idx] = exc + lds[t] - v;
    if (b == SCAN_NB - 1 && t == 255) off[N_NODES] = exc + total;
}

// ---------------- hot path: f16 MFMA edge kernel, 4 tiles/wave --------------

// Per wave: 64 edges = 4 tiles of 16 (R13 structure, verified). Messages now
// stored as f16 (halves the MSG round-trip: 51->26 MB written, gather reads
// halve too; per-message rounding is random and averages down through the
// deg-mean + pooling). Store = one 8B uint2 per tile per lane (quads of the
// same row are contiguous 32B).
__global__ __launch_bounds__(256) void edge_mfma6_kernel(
    const float* __restrict__ xin,
    const int* __restrict__ src,
    const int* __restrict__ dst,
    const int* __restrict__ rank,
    const int* __restrict__ off,
    const float* __restrict__ eattr,
    const float* __restrict__ AC,
    const unsigned int* __restrict__ WF,
    _Float16* __restrict__ msg_buf)
{
    __shared__ uint4 wf_s[832];                         // 13312 B
    const int tid = threadIdx.x;
    #pragma unroll
    for (int it = 0; it < 4; ++it) {
        int gi = tid + it*256;
        if (gi < 832) wf_s[gi] = ((const uint4*)WF)[gi];
    }
    __syncthreads();

    const int wave = tid >> 6;
    const int lane = tid & 63;
    const int q    = lane >> 4;
    const int el   = lane & 15;
    const int i0   = (q & 1) * 8;
    const bool bsel = (q >> 1) != 0;
    const int E0   = (blockIdx.x * 4 + wave) * 64;

    // coalesced scalar plane: lane L <-> edge E0+L
    const int sAll = src[E0 + lane];
    const int dAll = dst[E0 + lane];
    const int rAll = rank[E0 + lane];
    const int pAll = off[dAll] + rAll;     // CSR slot of edge E0+lane

    int   sT[4];
    float a0[4], a1[4], a2[4];
    #pragma unroll
    for (int t = 0; t < 4; ++t) {
        sT[t] = __shfl(sAll, t*16 + el);
        int e = E0 + t*16 + el;
        a0[t] = eattr[(size_t)e*3+0];
        a1[t] = eattr[(size_t)e*3+1];
        a2[t] = eattr[(size_t)e*3+2];
    }

    // xs gather + f16 RNE once per tile
    U4H8 xf[4];
    #pragma unroll
    for (int t = 0; t < 4; ++t) {
        const float4* xp = (const float4*)(xin + (size_t)sT[t]*16 + i0);
        const float4 xl = xp[0], xh = xp[1];
        const float x8[8] = {xl.x,xl.y,xl.z,xl.w,xh.x,xh.y,xh.z,xh.w};
        #pragma unroll
        for (int j = 0; j < 4; ++j) {
            half2v tv; tv.x = (_Float16)x8[2*j]; tv.y = (_Float16)x8[2*j+1];
            xf[t].p[j] = tv;
        }
    }

    f32x4 acc0 = {0.f,0.f,0.f,0.f}, acc1 = {0.f,0.f,0.f,0.f};
    f32x4 acc2 = {0.f,0.f,0.f,0.f}, acc3 = {0.f,0.f,0.f,0.f};
    #pragma unroll 1
    for (int m = 0; m < 13; ++m) {
        const float4 Ae = *(const float4*)(AC + m*8);
        const float4 Ao = *(const float4*)(AC + m*8 + 4);
        const float A0 = bsel ? Ao.x : Ae.x;
        const float A1 = bsel ? Ao.y : Ae.y;
        const float A2 = bsel ? Ao.z : Ae.z;
        const float A3 = bsel ? Ao.w : Ae.w;
        U4H8 w; w.u = wf_s[m*64 + lane];     // ds_read_b128 (LDS pipe)
        #pragma unroll
        for (int t = 0; t < 4; ++t) {
            float h = fmaxf(fmaf(a2[t], A2, fmaf(a1[t], A1,
                              fmaf(a0[t], A0, A3))), 0.f);
            _Float16 hh = (_Float16)h;
            half2v h2; h2.x = hh; h2.y = hh;
            U4H8 f;
            #pragma unroll
            for (int j = 0; j < 4; ++j) f.p[j] = h2 * xf[t].p[j];
            // swapped operands: D = W'^T @ H^T = msg^T (verified R13)
            f32x4 a = (t==0) ? acc0 : (t==1) ? acc1 : (t==2) ? acc2 : acc3;
            a = __builtin_amdgcn_mfma_f32_16x16x32_f16(w.h, f.h, a, 0, 0, 0);
            if (t==0) acc0 = a; else if (t==1) acc1 = a;
            else if (t==2) acc2 = a; else acc3 = a;
        }
    }

    // lane (q,el) holds msg[edge el][o=q*4..q*4+3] -> one 8B f16x4 store/tile
    #pragma unroll
    for (int t = 0; t < 4; ++t) {
        int row = __shfl(pAll, t*16 + el);
        f32x4 a = (t==0) ? acc0 : (t==1) ? acc1 : (t==2) ? acc2 : acc3;
        H2U2 cv;
        half2v c01; c01.x = (_Float16)a[0]; c01.y = (_Float16)a[1];
        half2v c23; c23.x = (_Float16)a[2]; c23.y = (_Float16)a[3];
        cv.p[0] = c01; cv.p[1] = c23;
        *(uint2*)(msg_buf + (size_t)row * HID_C + q*4) = cv.u;
    }
}

// 16 threads per node (lane = out channel). Segment-sum f16 msg rows
// [off[n], off[n+1]) -> mean -> + x@root + bias -> ELU.
__global__ __launch_bounds__(256) void node_gather_kernel(
    const float* __restrict__ xin, const _Float16* __restrict__ msg_buf,
    const int* __restrict__ off,
    const float* __restrict__ root, const float* __restrict__ bias,
    float* __restrict__ xout)
{
    int t = blockIdx.x * blockDim.x + threadIdx.x;
    int n = t >> 4;
    int o = t & 15;
    if (n >= N_NODES) return;
    int lo = off[n], hi = off[n+1];
    float inv = 1.f / fmaxf((float)(hi - lo), 1.f);

    float s0 = 0.f, s1 = 0.f, s2 = 0.f, s3 = 0.f;
    int r = lo;
    for (; r + 4 <= hi; r += 4) {
        s0 += (float)msg_buf[(size_t)r     * HID_C + o];
        s1 += (float)msg_buf[(size_t)(r+1) * HID_C + o];
        s2 += (float)msg_buf[(size_t)(r+2) * HID_C + o];
        s3 += (float)msg_buf[(size_t)(r+3) * HID_C + o];
    }
    for (; r < hi; ++r) s0 += (float)msg_buf[(size_t)r * HID_C + o];
    float s = (s0 + s1) + (s2 + s3);

    float acc = fmaf(s, inv, bias[o]);
    const float* xr = xin + (size_t)n * IN_C;
    #pragma unroll
    for (int i = 0; i < IN_C; ++i)
        acc = fmaf(xr[i], root[i*HID_C+o], acc);
    xout[(size_t)n*HID_C + o] = acc > 0.f ? acc : (expf(acc) - 1.f);
}

// fused: global mean pool (batch sorted -> contiguous segments) + final linear
__global__ __launch_bounds__(64) void pool_final_kernel(
    const float* __restrict__ xin, const int* __restrict__ goff,
    const float* __restrict__ fcW, const float* __restrict__ fcb,
    float* __restrict__ out)
{
    __shared__ float part[4][HID_C];
    __shared__ float pooled[HID_C];
    int g = blockIdx.x;
    int t = threadIdx.x;
    int c = t & 15, sub = t >> 4;
    int lo = goff[g], hi = goff[g+1];
    float s = 0.f;
    for (int n = lo + sub; n < hi; n += 4)
        s += xin[(size_t)n*HID_C + c];
    part[sub][c] = s;
    __syncthreads();
    if (t < HID_C) {
        pooled[t] = (part[0][t] + part[1][t] + part[2][t] + part[3][t])
                    / fmaxf((float)(hi - lo), 1.f);
    }
    __syncthreads();
    if (t < OUT_C) {
        float acc = fcb[t];
        #pragma unroll
        for (int i = 0; i < HID_C; ++i)
            acc = fmaf(pooled[i], fcW[i*OUT_C+t], acc);
        out[g*OUT_C + t] = acc;
    }
}

// ---------------- launch ----------------

extern "C" void kernel_launch(void* const* d_in, const int* in_sizes, int n_in,
                              void* d_out, int out_size, void* d_ws, size_t ws_size,
                              hipStream_t stream)
{
    const float* x     = (const float*)d_in[0];
    const int*   ei    = (const int*)d_in[1];
    const float* eattr = (const float*)d_in[2];
    const int*   batch = (const int*)d_in[3];
    const float* W1a   = (const float*)d_in[4];
    const float* b1a   = (const float*)d_in[5];
    const float* g1    = (const float*)d_in[6];
    const float* bt1   = (const float*)d_in[7];
    const float* m1    = (const float*)d_in[8];
    const float* v1    = (const float*)d_in[9];
    const float* W1b   = (const float*)d_in[10];
    const float* b1b   = (const float*)d_in[11];
    const float* root1 = (const float*)d_in[12];
    const float* bias1 = (const float*)d_in[13];
    const float* W2a   = (const float*)d_in[14];
    const float* b2a   = (const float*)d_in[15];
    const float* g2    = (const float*)d_in[16];
    const float* bt2   = (const float*)d_in[17];
    const float* m2    = (const float*)d_in[18];
    const float* v2    = (const float*)d_in[19];
    const float* W2b   = (const float*)d_in[20];
    const float* b2b   = (const float*)d_in[21];
    const float* root2 = (const float*)d_in[22];
    const float* bias2 = (const float*)d_in[23];
    const float* fcW   = (const float*)d_in[24];
    const float* fcb   = (const float*)d_in[25];

    const int* src = ei;
    const int* dst = ei + N_EDGES;

    float* ws   = (float*)d_ws;
    _Float16* MSG = (_Float16*)ws;                      // 12,800,000 h (25.6MB)
    float* X1   = ws + 12800000;                        //    800,000 f
    float* X2   = ws + 13600000;                        //    800,000 f
    int*   RANK = (int*)(ws + 14400000);                //    800,000 i
    int*   CNT  = (int*)(ws + 15200000);                //     50,000 i
    int*   OFF  = (int*)(ws + 15250000);                //     50,001 i (+pad)
    int*   GOFF = (int*)(ws + 15300064);                //        501 i (+pad)
    unsigned int* WF1 = (unsigned int*)(ws + 15300576); //      3,328 u (16B aligned)
    unsigned int* WF2 = (unsigned int*)(ws + 15303904); //      3,328 u
    float* AC1  = ws + 15307232;                        //        104 f (+pad)
    float* AC2  = ws + 15307344;                        //        104 f
    int*   AGG  = (int*)(ws + 15307456);                //        196 i (+pad)
    int*   PRE  = (int*)(ws + 15307712);                //        196 i (+pad)
    int*   FLAG = (int*)(ws + 15307968);                //        196 i
    // total ~15,308,164 f = 61.23 MB

    setup_kernel<<<9 + SCAN_NB, 256, 0, stream>>>(
        W1a, b1a, g1, bt1, m1, v1, W2a, b2a, g2, bt2, m2, v2,
        W1b, b1b, W2b, b2b, batch, AC1, AC2, WF1, WF2, GOFF, CNT, FLAG);
    rank_kernel<<<N_EDGES/256, 256, 0, stream>>>(dst, CNT, RANK);
    scan_single<<<SCAN_NB, 256, 0, stream>>>(CNT, OFF, AGG, PRE, FLAG);

    edge_mfma6_kernel<<<N_EDGES/256, 256, 0, stream>>>(x, src, dst, RANK, OFF,
                                                       eattr, AC1, WF1, MSG);
    node_gather_kernel<<<(N_NODES*16+255)/256, 256, 0, stream>>>(x, MSG, OFF,
                                                                 root1, bias1, X1);

    edge_mfma6_kernel<<<N_EDGES/256, 256, 0, stream>>>(X1, src, dst, RANK, OFF,
                                                       eattr, AC2, WF2, MSG);
    node_gather_kernel<<<(N_NODES*16+255)/256, 256, 0, stream>>>(X1, MSG, OFF,
                                                                 root2, bias2, X2);

    pool_final_kernel<<<N_GRAPHS, 64, 0, stream>>>(X2, GOFF, fcW, fcb, (float*)d_out);
}

// Round 15
// 260.961 us; speedup vs baseline: 1.0107x; 1.0107x over previous
//
#include <hip/hip_runtime.h>
#include <math.h>

#define N_NODES 50000
#define N_EDGES 800000
#define IN_C 16
#define HID_C 16
#define OUT_C 10
#define N_GRAPHS 500
#define EDGE_DIM 3
#define MLP_HID 25
#define BN_EPS 1e-5f

#define SCAN_NB ((N_NODES + 255) / 256)   // 196 blocks

typedef __attribute__((ext_vector_type(8))) _Float16 half8;
typedef __attribute__((ext_vector_type(2))) _Float16 half2v;
typedef __attribute__((ext_vector_type(4))) float f32x4;
union U4H8 { uint4 u; half8 h; half2v p[4]; };
union HU { _Float16 h; unsigned short u; };
union H2U2 { half2v p[2]; uint2 u; };

// ---------------- setup: W-pack(f16) + BN-fold + goff + zero CNT/flags -------

// blk 0..6  : pack W' = [Wb rows (k'=k*16+i, k<25) ; bb rows (k'=400+i)]
//             (416x16) into per-MFMA per-lane f16 fragments (RNE).
//             Element j of (m, lane L): row k'=32m+8(L>>4)+j, col o=L&15.
//             (Same data serves as the A-operand W'^T fragment — verified R13.)
// blk 7     : fold BN into AC[k][4]={A0,A1,A2,C} (k<25), AC[25]={0,0,0,1};
// blk 7..8  : goff[g] = lower_bound(batch, g) (batch sorted)
// blk 9..204: zero CNT; blk 9 also zeroes the scan lookback flags
__global__ __launch_bounds__(256) void setup_kernel(
    const float* __restrict__ W1a, const float* __restrict__ b1a,
    const float* __restrict__ g1, const float* __restrict__ bt1,
    const float* __restrict__ m1, const float* __restrict__ v1,
    const float* __restrict__ W2a, const float* __restrict__ b2a,
    const float* __restrict__ g2, const float* __restrict__ bt2,
    const float* __restrict__ m2, const float* __restrict__ v2,
    const float* __restrict__ W1b, const float* __restrict__ b1b,
    const float* __restrict__ W2b, const float* __restrict__ b2b,
    const int* __restrict__ batch,
    float* __restrict__ AC1, float* __restrict__ AC2,
    unsigned int* __restrict__ WF1, unsigned int* __restrict__ WF2,
    int* __restrict__ goff, int* __restrict__ cnt, int* __restrict__ flag)
{
    const int blk = blockIdx.x;
    const int tid = threadIdx.x;
    if (blk < 7) {
        int t = blk * 256 + tid;
        if (t >= 1664) return;
        const float *Wb, *bb; unsigned int *WH;
        int tl = t;
        if (t < 832) { Wb = W1b; bb = b1b; WH = WF1; }
        else { tl = t - 832; Wb = W2b; bb = b2b; WH = WF2; }
        int m = tl >> 6;
        int L = tl & 63;
        int q = L >> 4, o = L & 15;
        unsigned int hi[8];
        for (int j = 0; j < 8; ++j) {
            int kp = m*32 + q*8 + j;          // 0..415
            int k = kp >> 4, i = kp & 15;
            float w = (k < 25) ? Wb[k*256 + i*16 + o] : bb[i*16 + o];
            HU cv; cv.h = (_Float16)w;        // f16 RNE
            hi[j] = cv.u;
        }
        int base = (m*64 + L) * 4;
        for (int d = 0; d < 4; ++d)
            WH[base + d] = hi[2*d] | (hi[2*d+1] << 16);
        return;
    }
    if (blk == 7 || blk == 8) {
        if (blk == 7) {
            if (tid < 26) {
                int k = tid;
                if (k < 25) {
                    float sc = g1[k] / sqrtf(v1[k] + BN_EPS);
                    AC1[k*4+0] = sc * W1a[0*MLP_HID+k];
                    AC1[k*4+1] = sc * W1a[1*MLP_HID+k];
                    AC1[k*4+2] = sc * W1a[2*MLP_HID+k];
                    AC1[k*4+3] = sc * (b1a[k] - m1[k]) + bt1[k];
                } else {
                    AC1[100] = 0.f; AC1[101] = 0.f; AC1[102] = 0.f; AC1[103] = 1.f;
                }
            } else if (tid >= 32 && tid < 58) {
                int k = tid - 32;
                if (k < 25) {
                    float sc = g2[k] / sqrtf(v2[k] + BN_EPS);
                    AC2[k*4+0] = sc * W2a[0*MLP_HID+k];
                    AC2[k*4+1] = sc * W2a[1*MLP_HID+k];
                    AC2[k*4+2] = sc * W2a[2*MLP_HID+k];
                    AC2[k*4+3] = sc * (b2a[k] - m2[k]) + bt2[k];
                } else {
                    AC2[100] = 0.f; AC2[101] = 0.f; AC2[102] = 0.f; AC2[103] = 1.f;
                }
            }
        }
        int g = (blk - 7) * 256 + tid;
        if (g <= N_GRAPHS) {
            int lo = 0, hi = N_NODES;
            while (lo < hi) {
                int mid = (lo + hi) >> 1;
                if (batch[mid] < g) lo = mid + 1; else hi = mid;
            }
            goff[g] = lo;
        }
        return;
    }
    int idx = (blk - 9) * 256 + tid;
    if (idx < N_NODES) cnt[idx] = 0;
    if (blk == 9 && tid < SCAN_NB) flag[tid] = 0;
}

// ---------------- CSR build ----------------

__global__ __launch_bounds__(256) void rank_kernel(const int* __restrict__ dst,
                                                   int* __restrict__ cnt,
                                                   int* __restrict__ rank) {
    int e = blockIdx.x * blockDim.x + threadIdx.x;
    if (e < N_EDGES) rank[e] = atomicAdd(&cnt[dst[e]], 1);
}

// single-pass exclusive scan of cnt -> off[0..N] via decoupled lookback
// (verified R14). flag[b]: 0=none, 1=aggregate ready, 2=prefix ready.
__global__ __launch_bounds__(256) void scan_single(const int* __restrict__ cnt,
                                                   int* __restrict__ off,
                                                   int* __restrict__ agg,
                                                   int* __restrict__ pre,
                                                   int* __restrict__ flag) {
    __shared__ int lds[256];
    __shared__ int sExc;
    const int b = blockIdx.x, t = threadIdx.x;
    const int idx = b * 256 + t;
    const int v = (idx < N_NODES) ? cnt[idx] : 0;
    lds[t] = v;
    __syncthreads();
    for (int d = 1; d < 256; d <<= 1) {
        int u = (t >= d) ? lds[t - d] : 0;
        __syncthreads();
        lds[t] += u;
        __syncthreads();
    }
    const int total = lds[255];
    if (t == 0) {
        int exc = 0;
        if (b == 0) {
            atomicExch(&pre[0], total);
            __threadfence();
            atomicExch(&flag[0], 2);
        } else {
            atomicExch(&agg[b], total);
            __threadfence();
            atomicExch(&flag[b], 1);
            int j = b - 1;
            while (true) {
                int f;
                do { f = atomicAdd(&flag[j], 0); } while (f == 0);
                if (f == 2) { exc += atomicAdd(&pre[j], 0); break; }
                exc += atomicAdd(&agg[j], 0);
                --j;
            }
            atomicExch(&pre[b], exc + total);
            __threadfence();
            atomicExch(&flag[b], 2);
        }
        sExc = exc;
    }
    __syncthreads();
    const int exc = sExc;
    if (idx < N_NODES) off[idx] = exc + lds[t] - v;
    if (b == SCAN_NB - 1 && t == 255) off[N_NODES] = exc + total;
}

// ---------------- hot path: f16 MFMA edge kernel, 4 tiles/wave --------------

// (R13/R14 structure, verified.) Per wave: 64 edges = 4 tiles of 16. WF
// fragments staged in LDS once per block; MFMA operands swapped so lane
// (q,el) holds msg[edge el][o=q*4..+3]; f16 message store = one 8B uint2
// per tile per lane.
__global__ __launch_bounds__(256) void edge_mfma6_kernel(
    const float* __restrict__ xin,
    const int* __restrict__ src,
    const int* __restrict__ dst,
    const int* __restrict__ rank,
    const int* __restrict__ off,
    const float* __restrict__ eattr,
    const float* __restrict__ AC,
    const unsigned int* __restrict__ WF,
    _Float16* __restrict__ msg_buf)
{
    __shared__ uint4 wf_s[832];                         // 13312 B
    const int tid = threadIdx.x;
    #pragma unroll
    for (int it = 0; it < 4; ++it) {
        int gi = tid + it*256;
        if (gi < 832) wf_s[gi] = ((const uint4*)WF)[gi];
    }
    __syncthreads();

    const int wave = tid >> 6;
    const int lane = tid & 63;
    const int q    = lane >> 4;
    const int el   = lane & 15;
    const int i0   = (q & 1) * 8;
    const bool bsel = (q >> 1) != 0;
    const int E0   = (blockIdx.x * 4 + wave) * 64;

    const int sAll = src[E0 + lane];
    const int dAll = dst[E0 + lane];
    const int rAll = rank[E0 + lane];
    const int pAll = off[dAll] + rAll;     // CSR slot of edge E0+lane

    int   sT[4];
    float a0[4], a1[4], a2[4];
    #pragma unroll
    for (int t = 0; t < 4; ++t) {
        sT[t] = __shfl(sAll, t*16 + el);
        int e = E0 + t*16 + el;
        a0[t] = eattr[(size_t)e*3+0];
        a1[t] = eattr[(size_t)e*3+1];
        a2[t] = eattr[(size_t)e*3+2];
    }

    U4H8 xf[4];
    #pragma unroll
    for (int t = 0; t < 4; ++t) {
        const float4* xp = (const float4*)(xin + (size_t)sT[t]*16 + i0);
        const float4 xl = xp[0], xh = xp[1];
        const float x8[8] = {xl.x,xl.y,xl.z,xl.w,xh.x,xh.y,xh.z,xh.w};
        #pragma unroll
        for (int j = 0; j < 4; ++j) {
            half2v tv; tv.x = (_Float16)x8[2*j]; tv.y = (_Float16)x8[2*j+1];
            xf[t].p[j] = tv;
        }
    }

    f32x4 acc0 = {0.f,0.f,0.f,0.f}, acc1 = {0.f,0.f,0.f,0.f};
    f32x4 acc2 = {0.f,0.f,0.f,0.f}, acc3 = {0.f,0.f,0.f,0.f};
    #pragma unroll 1
    for (int m = 0; m < 13; ++m) {
        const float4 Ae = *(const float4*)(AC + m*8);
        const float4 Ao = *(const float4*)(AC + m*8 + 4);
        const float A0 = bsel ? Ao.x : Ae.x;
        const float A1 = bsel ? Ao.y : Ae.y;
        const float A2 = bsel ? Ao.z : Ae.z;
        const float A3 = bsel ? Ao.w : Ae.w;
        U4H8 w; w.u = wf_s[m*64 + lane];     // ds_read_b128 (LDS pipe)
        #pragma unroll
        for (int t = 0; t < 4; ++t) {
            float h = fmaxf(fmaf(a2[t], A2, fmaf(a1[t], A1,
                              fmaf(a0[t], A0, A3))), 0.f);
            _Float16 hh = (_Float16)h;
            half2v h2; h2.x = hh; h2.y = hh;
            U4H8 f;
            #pragma unroll
            for (int j = 0; j < 4; ++j) f.p[j] = h2 * xf[t].p[j];
            f32x4 a = (t==0) ? acc0 : (t==1) ? acc1 : (t==2) ? acc2 : acc3;
            a = __builtin_amdgcn_mfma_f32_16x16x32_f16(w.h, f.h, a, 0, 0, 0);
            if (t==0) acc0 = a; else if (t==1) acc1 = a;
            else if (t==2) acc2 = a; else acc3 = a;
        }
    }

    #pragma unroll
    for (int t = 0; t < 4; ++t) {
        int row = __shfl(pAll, t*16 + el);
        f32x4 a = (t==0) ? acc0 : (t==1) ? acc1 : (t==2) ? acc2 : acc3;
        H2U2 cv;
        half2v c01; c01.x = (_Float16)a[0]; c01.y = (_Float16)a[1];
        half2v c23; c23.x = (_Float16)a[2]; c23.y = (_Float16)a[3];
        cv.p[0] = c01; cv.p[1] = c23;
        *(uint2*)(msg_buf + (size_t)row * HID_C + q*4) = cv.u;
    }
}

// 4 lanes per node (lane = channel quad). Per deg-iter one 8B uint2 load/lane
// -> a wave instruction moves 512B serving 16 nodes (old f16 layout: 128B /
// 4 nodes). x row: 4 float4 instr/wave; store: one float4 per lane.
// VMEM instr/node ~8 -> ~2.5.
__global__ __launch_bounds__(256) void node_gather_kernel(
    const float* __restrict__ xin, const _Float16* __restrict__ msg_buf,
    const int* __restrict__ off,
    const float* __restrict__ root, const float* __restrict__ bias,
    float* __restrict__ xout)
{
    int t = blockIdx.x * blockDim.x + threadIdx.x;
    int n = t >> 2;
    int quad = t & 3;
    if (n >= N_NODES) return;
    int lo = off[n], hi = off[n+1];
    float inv = 1.f / fmaxf((float)(hi - lo), 1.f);

    f32x4 s0 = {0.f,0.f,0.f,0.f}, s1 = {0.f,0.f,0.f,0.f};
    int r = lo;
    for (; r + 2 <= hi; r += 2) {
        H2U2 c0; c0.u = *(const uint2*)(msg_buf + (size_t)r     * HID_C + quad*4);
        H2U2 c1; c1.u = *(const uint2*)(msg_buf + (size_t)(r+1) * HID_C + quad*4);
        s0[0] += (float)c0.p[0].x; s0[1] += (float)c0.p[0].y;
        s0[2] += (float)c0.p[1].x; s0[3] += (float)c0.p[1].y;
        s1[0] += (float)c1.p[0].x; s1[1] += (float)c1.p[0].y;
        s1[2] += (float)c1.p[1].x; s1[3] += (float)c1.p[1].y;
    }
    if (r < hi) {
        H2U2 c0; c0.u = *(const uint2*)(msg_buf + (size_t)r * HID_C + quad*4);
        s0[0] += (float)c0.p[0].x; s0[1] += (float)c0.p[0].y;
        s0[2] += (float)c0.p[1].x; s0[3] += (float)c0.p[1].y;
    }

    const float4 bi = *(const float4*)(bias + quad*4);
    float acc0 = fmaf(s0[0] + s1[0], inv, bi.x);
    float acc1 = fmaf(s0[1] + s1[1], inv, bi.y);
    float acc2 = fmaf(s0[2] + s1[2], inv, bi.z);
    float acc3 = fmaf(s0[3] + s1[3], inv, bi.w);

    const float4* xp = (const float4*)(xin + (size_t)n * IN_C);
    const float4 x0 = xp[0], x1 = xp[1], x2 = xp[2], x3 = xp[3];
    const float xr[16] = {x0.x,x0.y,x0.z,x0.w, x1.x,x1.y,x1.z,x1.w,
                          x2.x,x2.y,x2.z,x2.w, x3.x,x3.y,x3.z,x3.w};
    #pragma unroll
    for (int i = 0; i < IN_C; ++i) {
        const float4 rr = *(const float4*)(root + i*HID_C + quad*4);  // L1-hot
        acc0 = fmaf(xr[i], rr.x, acc0);
        acc1 = fmaf(xr[i], rr.y, acc1);
        acc2 = fmaf(xr[i], rr.z, acc2);
        acc3 = fmaf(xr[i], rr.w, acc3);
    }
    float4 ov;
    ov.x = acc0 > 0.f ? acc0 : (expf(acc0) - 1.f);
    ov.y = acc1 > 0.f ? acc1 : (expf(acc1) - 1.f);
    ov.z = acc2 > 0.f ? acc2 : (expf(acc2) - 1.f);
    ov.w = acc3 > 0.f ? acc3 : (expf(acc3) - 1.f);
    *(float4*)(xout + (size_t)n*HID_C + quad*4) = ov;
}

// fused: global mean pool (batch sorted -> contiguous segments) + final linear
__global__ __launch_bounds__(64) void pool_final_kernel(
    const float* __restrict__ xin, const int* __restrict__ goff,
    const float* __restrict__ fcW, const float* __restrict__ fcb,
    float* __restrict__ out)
{
    __shared__ float part[4][HID_C];
    __shared__ float pooled[HID_C];
    int g = blockIdx.x;
    int t = threadIdx.x;
    int c = t & 15, sub = t >> 4;
    int lo = goff[g], hi = goff[g+1];
    float s = 0.f;
    for (int n = lo + sub; n < hi; n += 4)
        s += xin[(size_t)n*HID_C + c];
    part[sub][c] = s;
    __syncthreads();
    if (t < HID_C) {
        pooled[t] = (part[0][t] + part[1][t] + part[2][t] + part[3][t])
                    / fmaxf((float)(hi - lo), 1.f);
    }
    __syncthreads();
    if (t < OUT_C) {
        float acc = fcb[t];
        #pragma unroll
        for (int i = 0; i < HID_C; ++i)
            acc = fmaf(pooled[i], fcW[i*OUT_C+t], acc);
        out[g*OUT_C + t] = acc;
    }
}

// ---------------- launch ----------------

extern "C" void kernel_launch(void* const* d_in, const int* in_sizes, int n_in,
                              void* d_out, int out_size, void* d_ws, size_t ws_size,
                              hipStream_t stream)
{
    const float* x     = (const float*)d_in[0];
    const int*   ei    = (const int*)d_in[1];
    const float* eattr = (const float*)d_in[2];
    const int*   batch = (const int*)d_in[3];
    const float* W1a   = (const float*)d_in[4];
    const float* b1a   = (const float*)d_in[5];
    const float* g1    = (const float*)d_in[6];
    const float* bt1   = (const float*)d_in[7];
    const float* m1    = (const float*)d_in[8];
    const float* v1    = (const float*)d_in[9];
    const float* W1b   = (const float*)d_in[10];
    const float* b1b   = (const float*)d_in[11];
    const float* root1 = (const float*)d_in[12];
    const float* bias1 = (const float*)d_in[13];
    const float* W2a   = (const float*)d_in[14];
    const float* b2a   = (const float*)d_in[15];
    const float* g2    = (const float*)d_in[16];
    const float* bt2   = (const float*)d_in[17];
    const float* m2    = (const float*)d_in[18];
    const float* v2    = (const float*)d_in[19];
    const float* W2b   = (const float*)d_in[20];
    const float* b2b   = (const float*)d_in[21];
    const float* root2 = (const float*)d_in[22];
    const float* bias2 = (const float*)d_in[23];
    const float* fcW   = (const float*)d_in[24];
    const float* fcb   = (const float*)d_in[25];

    const int* src = ei;
    const int* dst = ei + N_EDGES;

    float* ws   = (float*)d_ws;
    _Float16* MSG = (_Float16*)ws;                      // 12,800,000 h (25.6MB)
    float* X1   = ws + 12800000;                        //    800,000 f
    float* X2   = ws + 13600000;                        //    800,000 f
    int*   RANK = (int*)(ws + 14400000);                //    800,000 i
    int*   CNT  = (int*)(ws + 15200000);                //     50,000 i
    int*   OFF  = (int*)(ws + 15250000);                //     50,001 i (+pad)
    int*   GOFF = (int*)(ws + 15300064);                //        501 i (+pad)
    unsigned int* WF1 = (unsigned int*)(ws + 15300576); //      3,328 u (16B aligned)
    unsigned int* WF2 = (unsigned int*)(ws + 15303904); //      3,328 u
    float* AC1  = ws + 15307232;                        //        104 f (+pad)
    float* AC2  = ws + 15307344;                        //        104 f
    int*   AGG  = (int*)(ws + 15307456);                //        196 i (+pad)
    int*   PRE  = (int*)(ws + 15307712);                //        196 i (+pad)
    int*   FLAG = (int*)(ws + 15307968);                //        196 i
    // total ~15,308,164 f = 61.23 MB

    setup_kernel<<<9 + SCAN_NB, 256, 0, stream>>>(
        W1a, b1a, g1, bt1, m1, v1, W2a, b2a, g2, bt2, m2, v2,
        W1b, b1b, W2b, b2b, batch, AC1, AC2, WF1, WF2, GOFF, CNT, FLAG);
    rank_kernel<<<N_EDGES/256, 256, 0, stream>>>(dst, CNT, RANK);
    scan_single<<<SCAN_NB, 256, 0, stream>>>(CNT, OFF, AGG, PRE, FLAG);

    edge_mfma6_kernel<<<N_EDGES/256, 256, 0, stream>>>(x, src, dst, RANK, OFF,
                                                       eattr, AC1, WF1, MSG);
    node_gather_kernel<<<(N_NODES*4+255)/256, 256, 0, stream>>>(x, MSG, OFF,
                                                                root1, bias1, X1);

    edge_mfma6_kernel<<<N_EDGES/256, 256, 0, stream>>>(X1, src, dst, RANK, OFF,
                                                       eattr, AC2, WF2, MSG);
    node_gather_kernel<<<(N_NODES*4+255)/256, 256, 0, stream>>>(X1, MSG, OFF,
                                                                root2, bias2, X2);

    pool_final_kernel<<<N_GRAPHS, 64, 0, stream>>>(X2, GOFF, fcW, fcb, (float*)d_out);
}